// Round 1
// baseline (303.332 us; speedup 1.0000x reference)
//
#include <hip/hip_runtime.h>
#include <hip/hip_bf16.h>
#include <math.h>

typedef __bf16 bf16_t;
typedef bf16_t bf16x8 __attribute__((ext_vector_type(8)));
typedef float f32x4 __attribute__((ext_vector_type(4)));

#define BB 4
#define SS 2048
#define HH 16
#define DMODEL 1024
#define DHEAD 64

// Q is pre-scaled by 1/sqrt(64) * log2(e) so attention probs are exp2(q.k)
#define QSCALE 0.18033688011112042f

__device__ inline unsigned short f2bf(float f) {
    union { __hip_bfloat16 h; unsigned short u; } cvt;
    cvt.h = __float2bfloat16(f);
    return cvt.u;
}

// async global->LDS, 16B per lane. LDS dest = wave-uniform base + lane*16.
__device__ __forceinline__ void gll16(const unsigned short* g, unsigned short* l) {
    __builtin_amdgcn_global_load_lds(
        (const __attribute__((address_space(1))) unsigned int*)(g),
        (__attribute__((address_space(3))) unsigned int*)(l), 16, 0, 0);
}

// ---------------- pack kernels ----------------

__global__ void pack_x(const float* __restrict__ x, unsigned short* __restrict__ xb) {
    int i = blockIdx.x * 256 + threadIdx.x;
    const float4 v = ((const float4*)x)[i];
    unsigned short o[4] = { f2bf(v.x), f2bf(v.y), f2bf(v.z), f2bf(v.w) };
    *(uint2*)(xb + 4 * (size_t)i) = *(uint2*)o;
}

// WqkvT[n][k], n = mat*1024 + h*64 + d, k = m.  W_* is [H][DM][DH].
__global__ void pack_wqkv(const float* __restrict__ wq, const float* __restrict__ wk,
                          const float* __restrict__ wv, unsigned short* __restrict__ out) {
    int idx = blockIdx.x * 256 + threadIdx.x;
    int k  = idx & 1023;
    int n  = idx >> 10;
    int mat = n >> 10;
    int n1 = n & 1023;
    int h = n1 >> 6, d = n1 & 63;
    const float* w = (mat == 0) ? wq : (mat == 1) ? wk : wv;
    out[idx] = f2bf(w[(h << 16) + (k << 6) + d]);
}

// WoT[n][k], n = m_model, k = h*64+dh.  W_O is [H][DH][DM] = row-major [k][n].
__global__ void pack_wo(const float* __restrict__ wo, unsigned short* __restrict__ out) {
    int idx = blockIdx.x * 256 + threadIdx.x;
    int k = idx & 1023, n = idx >> 10;
    out[idx] = f2bf(wo[(k << 10) + n]);
}

// ---------------- GEMM 1 (m97 structure): 128x128 tile, global_load_lds ----------------
// qkv = x @ WqkvT^T + bias.  Q (pre-scaled by QSCALE), K -> [B,H,S,64]; V -> [B,H,64,S].

__global__ __launch_bounds__(256) void gemm_qkv(
    const unsigned short* __restrict__ xb,    // [8192][1024]
    const unsigned short* __restrict__ wT,    // [3072][1024]
    const float* __restrict__ bq, const float* __restrict__ bk, const float* __restrict__ bv,
    unsigned short* __restrict__ qws, unsigned short* __restrict__ kws,
    unsigned short* __restrict__ vtw)         // [64][64][2048]
{
    __shared__ __align__(16) unsigned short lA[128 * 32];   // lane-linear, no pad (gll constraint)
    __shared__ __align__(16) unsigned short lB[128 * 32];
    const int t = threadIdx.x;
    const int lane = t & 63;
    const int w = t >> 6;
    const int quad = lane >> 4;
    const int l15 = lane & 15;
    const int n0 = blockIdx.x * 128;
    const int m0 = blockIdx.y * 128;
    const int wm = (w >> 1) * 64;
    const int wn = (w & 1) * 64;
    const int mat = n0 >> 10;                 // uniform per block (1024 % 128 == 0)

    f32x4 acc[4][4] = {};

    const int srow = w * 16 + (lane >> 2);
    const int scol = (lane & 3) * 8;
    const unsigned short* Ag0 = xb + (size_t)(m0 + srow) * 1024 + scol;
    const unsigned short* Ag1 = Ag0 + (size_t)64 * 1024;
    const unsigned short* Bg0 = wT + (size_t)(n0 + srow) * 1024 + scol;
    const unsigned short* Bg1 = Bg0 + (size_t)64 * 1024;
    unsigned short* lA0 = lA + (w * 16) * 32;
    unsigned short* lA1 = lA + (64 + w * 16) * 32;
    unsigned short* lB0 = lB + (w * 16) * 32;
    unsigned short* lB1 = lB + (64 + w * 16) * 32;

    if (mat != 2) {
        // swapped operands: D[m=weight n][n=x row s]
        for (int kt = 0; kt < 1024; kt += 32) {
            __syncthreads();
            gll16(Ag0 + kt, lA0);
            gll16(Ag1 + kt, lA1);
            gll16(Bg0 + kt, lB0);
            gll16(Bg1 + kt, lB1);
            __syncthreads();
            bf16x8 af[4], bfr[4];
#pragma unroll
            for (int i = 0; i < 4; i++) {
                af[i]  = *(const bf16x8*)(lA + (wm + i * 16 + l15) * 32 + quad * 8);
                bfr[i] = *(const bf16x8*)(lB + (wn + i * 16 + l15) * 32 + quad * 8);
            }
#pragma unroll
            for (int i = 0; i < 4; i++)
#pragma unroll
                for (int j = 0; j < 4; j++)
                    acc[i][j] = __builtin_amdgcn_mfma_f32_16x16x32_bf16(bfr[j], af[i], acc[i][j], 0, 0, 0);
        }
        // epilogue: lane holds 4 consecutive d at fixed s -> uint2 stores
        const int b = m0 >> 11;
        const float* bias_p = (mat == 0) ? bq : bk;
        const float scale = (mat == 0) ? QSCALE : 1.0f;   // fold softmax scale+log2e into Q
        unsigned short* dst = (mat == 0) ? qws : kws;
#pragma unroll
        for (int j = 0; j < 4; j++) {
            const int noff = wn + j * 16 + quad * 4;          // 0..124, quad*4+j*16 < 64
            const int h = noff >> 6;                           // head within this n-block pair
            const int hglob = ((n0 & 1023) >> 6) + h;
            const int dbase = noff & 63;
            const float4 bv4 = *(const float4*)(bias_p + hglob * 64 + dbase);
            const float bias_r[4] = { bv4.x, bv4.y, bv4.z, bv4.w };
#pragma unroll
            for (int i = 0; i < 4; i++) {
                const int s = (m0 & 2047) + wm + i * 16 + l15;
                unsigned short pk[4];
#pragma unroll
                for (int r = 0; r < 4; r++) pk[r] = f2bf((acc[i][j][r] + bias_r[r]) * scale);
                *(uint2*)(dst + (size_t)((b * 16 + hglob) * 2048 + s) * 64 + dbase) = *(uint2*)pk;
            }
        }
    } else {
        // normal order: D[m=x row s][n=weight] -> 4 consecutive s at fixed d -> uint2 into V^T
        for (int kt = 0; kt < 1024; kt += 32) {
            __syncthreads();
            gll16(Ag0 + kt, lA0);
            gll16(Ag1 + kt, lA1);
            gll16(Bg0 + kt, lB0);
            gll16(Bg1 + kt, lB1);
            __syncthreads();
            bf16x8 af[4], bfr[4];
#pragma unroll
            for (int i = 0; i < 4; i++) {
                af[i]  = *(const bf16x8*)(lA + (wm + i * 16 + l15) * 32 + quad * 8);
                bfr[i] = *(const bf16x8*)(lB + (wn + i * 16 + l15) * 32 + quad * 8);
            }
#pragma unroll
            for (int i = 0; i < 4; i++)
#pragma unroll
                for (int j = 0; j < 4; j++)
                    acc[i][j] = __builtin_amdgcn_mfma_f32_16x16x32_bf16(af[i], bfr[j], acc[i][j], 0, 0, 0);
        }
        const int b = m0 >> 11;
#pragma unroll
        for (int j = 0; j < 4; j++) {
            const int n1 = (n0 & 1023) + wn + j * 16 + l15;
            const int h = n1 >> 6, d = n1 & 63;
            const float bias = bv[h * 64 + d];
#pragma unroll
            for (int i = 0; i < 4; i++) {
                const int s0 = (m0 & 2047) + wm + i * 16 + quad * 4;
                unsigned short pk[4];
#pragma unroll
                for (int r = 0; r < 4; r++) pk[r] = f2bf(acc[i][j][r] + bias);
                *(uint2*)(vtw + ((size_t)(b * 16 + h) * 64 + d) * 2048 + s0) = *(uint2*)pk;
            }
        }
    }
}

// ---------------- attention v5 ----------------
// vs v4: (a) XOR-swizzled unpadded LDS tiles (kills the stride-72 4-way bank
// conflicts: 16B granule g stored at g^(row&7)), (b) register prefetch of next
// chunk's K/V under current chunk's compute with raw s_barrier + manual
// lgkmcnt so the global loads stay in flight across barriers (T14), (c) probs
// via exp2 on pre-scaled Q (no per-element scale mul), (d) setprio around MFMA.

__global__ __launch_bounds__(256) void attn3(
    const unsigned short* __restrict__ qws,
    const unsigned short* __restrict__ kws,
    const unsigned short* __restrict__ vtw,   // [bh][64][2048]
    unsigned short* __restrict__ zb)          // [8192][1024], col = h*64+d
{
    __shared__ __align__(16) unsigned short Ks[64 * 64];
    __shared__ __align__(16) unsigned short Vs[64 * 64];    // [d][key]
    __shared__ __align__(16) unsigned short Ps[4 * 16 * 64];

    const int t = threadIdx.x;
    const int lane = t & 63;
    const int w = t >> 6;
    const int quad = lane >> 4;
    const int l15 = lane & 15;
    const int hi = l15 >> 3;
    const int lo = l15 & 7;

    const int qt = 31 - (blockIdx.x >> 6);   // longest blocks dispatched first
    const int bh = blockIdx.x & 63;
    const int q0 = qt * 64;
    const int qbase = q0 + w * 16;
    const size_t base = (size_t)bh * SS * DHEAD;
    const unsigned short* Q = qws + base;
    const unsigned short* K = kws + base;
    const unsigned short* Vt = vtw + base;   // [64][2048]

    bf16x8 qf0 = *(const bf16x8*)(Q + (size_t)(qbase + l15) * 64 + quad * 8);
    bf16x8 qf1 = *(const bf16x8*)(Q + (size_t)(qbase + l15) * 64 + 32 + quad * 8);

    f32x4 o[4] = {};          // swapped PV: o[dt] rows = d (dt*16+quad*4+r), col = q (l15)
    float lsum[4] = {0.f, 0.f, 0.f, 0.f};
    unsigned short* Pw = Ps + w * 16 * 64;

    // staging: thread t covers row sr, original col-granules (t&3) and (t&3)+4
    const int sr = t >> 2;
    const int g0 = t & 3;
    const int sw0 = ((g0 ^ (sr & 7)) << 3);
    const int sw1 = (((g0 + 4) ^ (sr & 7)) << 3);
    unsigned short* ksw = Ks + sr * 64;
    unsigned short* vsw = Vs + sr * 64;
    const unsigned short* Kg = K + (size_t)sr * 64 + g0 * 8;
    const unsigned short* Vg = Vt + (size_t)sr * 2048 + g0 * 8;

    // fragment reads: want original granules quad / quad+4 of row with row&7==l15&7
    const int gq0 = ((quad ^ lo) << 3);
    const int gq1 = (((quad + 4) ^ lo) << 3);

    const int nch = qt + 1;

    // prologue: prefetch chunk 0 into registers
    uint4 kr0 = *(const uint4*)(Kg);
    uint4 kr1 = *(const uint4*)(Kg + 32);
    uint4 vr0 = *(const uint4*)(Vg);
    uint4 vr1 = *(const uint4*)(Vg + 32);

    for (int c = 0; c < nch; c++) {
        __builtin_amdgcn_sched_barrier(0);
        __builtin_amdgcn_s_barrier();          // LDS free: all waves consumed chunk c-1
        // write staged regs (compiler inserts the vmcnt wait here, after a full
        // compute phase of latency hiding)
        *(uint4*)(ksw + sw0) = kr0;
        *(uint4*)(ksw + sw1) = kr1;
        *(uint4*)(vsw + sw0) = vr0;
        *(uint4*)(vsw + sw1) = vr1;
        if (c + 1 < nch) {                     // issue next chunk's loads; NOT waited here
            const unsigned short* kp = Kg + (size_t)(c + 1) * 64 * 64;
            const unsigned short* vp = Vg + (size_t)(c + 1) * 64;
            kr0 = *(const uint4*)(kp);
            kr1 = *(const uint4*)(kp + 32);
            vr0 = *(const uint4*)(vp);
            vr1 = *(const uint4*)(vp + 32);
        }
        asm volatile("s_waitcnt lgkmcnt(0)" ::: "memory");   // my ds_writes done (vmcnt stays)
        __builtin_amdgcn_s_barrier();          // LDS ready
        __builtin_amdgcn_sched_barrier(0);

        // scores for 16 q-rows x 64 keys: 8 MFMA (D: row=q quad*4+r, col=key l15)
        f32x4 s[4];
        __builtin_amdgcn_s_setprio(1);
#pragma unroll
        for (int sub = 0; sub < 4; sub++) {
            const unsigned short* kr = Ks + (sub * 16 + l15) * 64;
            bf16x8 kf0 = *(const bf16x8*)(kr + gq0);
            bf16x8 kf1 = *(const bf16x8*)(kr + gq1);
            f32x4 sv = {};
            sv = __builtin_amdgcn_mfma_f32_16x16x32_bf16(qf0, kf0, sv, 0, 0, 0);
            sv = __builtin_amdgcn_mfma_f32_16x16x32_bf16(qf1, kf1, sv, 0, 0, 0);
            s[sub] = sv;
        }
        __builtin_amdgcn_s_setprio(0);

        // fixed-max softmax: p = exp2(s) since Q carries 0.125*log2e
        const int kb = c * 64;
        if (c == nch - 1) {
            const int qg = qbase + quad * 4;
#pragma unroll
            for (int sub = 0; sub < 4; sub++) {
                const int key = kb + sub * 16 + l15;
#pragma unroll
                for (int r = 0; r < 4; r++) {
                    float p = (key > qg + r) ? 0.f : exp2f(s[sub][r]);
                    lsum[r] += p;
                    const int q = quad * 4 + r;
                    Pw[q * 64 + (((sub * 2 + hi) ^ (q & 7)) << 3) + lo] = f2bf(p);
                }
            }
        } else {
#pragma unroll
            for (int sub = 0; sub < 4; sub++)
#pragma unroll
                for (int r = 0; r < 4; r++) {
                    float p = exp2f(s[sub][r]);
                    lsum[r] += p;
                    const int q = quad * 4 + r;
                    Pw[q * 64 + (((sub * 2 + hi) ^ (q & 7)) << 3) + lo] = f2bf(p);
                }
        }
        // wave-private D-layout -> fragment-layout round trip
        asm volatile("s_waitcnt lgkmcnt(0)" ::: "memory");
        bf16x8 pf0 = *(const bf16x8*)(Pw + l15 * 64 + gq0);
        bf16x8 pf1 = *(const bf16x8*)(Pw + l15 * 64 + gq1);
        __builtin_amdgcn_s_setprio(1);
#pragma unroll
        for (int dt = 0; dt < 4; dt++) {
            const unsigned short* vrp = Vs + (dt * 16 + l15) * 64;
            bf16x8 vf0 = *(const bf16x8*)(vrp + gq0);
            bf16x8 vf1 = *(const bf16x8*)(vrp + gq1);
            // swapped: A=V (m=d), B=P (n=q)
            o[dt] = __builtin_amdgcn_mfma_f32_16x16x32_bf16(vf0, pf0, o[dt], 0, 0, 0);
            o[dt] = __builtin_amdgcn_mfma_f32_16x16x32_bf16(vf1, pf1, o[dt], 0, 0, 0);
        }
        __builtin_amdgcn_s_setprio(0);
    }

    // full row sums (valid per lane for q = quad*4+r after 16-lane reduce)
#pragma unroll
    for (int r = 0; r < 4; r++) {
        float v = lsum[r];
        v += __shfl_xor(v, 1);
        v += __shfl_xor(v, 2);
        v += __shfl_xor(v, 4);
        v += __shfl_xor(v, 8);
        lsum[r] = v;
    }
    // redistribute: this lane needs 1/sum for q = l15
    const int srcl = (l15 >> 2) << 4;
    float t0 = __shfl(lsum[0], srcl);
    float t1 = __shfl(lsum[1], srcl);
    float t2 = __shfl(lsum[2], srcl);
    float t3 = __shfl(lsum[3], srcl);
    const int rr = l15 & 3;
    float den = (rr == 0) ? t0 : (rr == 1) ? t1 : (rr == 2) ? t2 : t3;
    const float inv = 1.0f / den;

    const int b = bh >> 4, h = bh & 15;
    const int q = qbase + l15;
    unsigned short* zrow = zb + (size_t)(b * 2048 + q) * 1024 + h * 64 + quad * 4;
#pragma unroll
    for (int dt = 0; dt < 4; dt++) {
        unsigned short pk[4];
#pragma unroll
        for (int r = 0; r < 4; r++) pk[r] = f2bf(o[dt][r] * inv);
        *(uint2*)(zrow + dt * 16) = *(uint2*)pk;
    }
}

// ---------------- GEMM 2 (m97 structure, swapped operands): out = z @ WoT^T + bO ----------------

__global__ __launch_bounds__(256) void gemm_out(
    const unsigned short* __restrict__ zb,    // [8192][1024]
    const unsigned short* __restrict__ wT,    // [1024][1024]
    const float* __restrict__ bo,
    float* __restrict__ out)
{
    __shared__ __align__(16) unsigned short lA[128 * 32];
    __shared__ __align__(16) unsigned short lB[128 * 32];
    const int t = threadIdx.x;
    const int lane = t & 63;
    const int w = t >> 6;
    const int quad = lane >> 4;
    const int l15 = lane & 15;
    const int n0 = blockIdx.x * 128;
    const int m0 = blockIdx.y * 128;
    const int wm = (w >> 1) * 64;
    const int wn = (w & 1) * 64;

    f32x4 acc[4][4] = {};

    const int srow = w * 16 + (lane >> 2);
    const int scol = (lane & 3) * 8;
    const unsigned short* Ag0 = zb + (size_t)(m0 + srow) * 1024 + scol;
    const unsigned short* Ag1 = Ag0 + (size_t)64 * 1024;
    const unsigned short* Bg0 = wT + (size_t)(n0 + srow) * 1024 + scol;
    const unsigned short* Bg1 = Bg0 + (size_t)64 * 1024;
    unsigned short* lA0 = lA + (w * 16) * 32;
    unsigned short* lA1 = lA + (64 + w * 16) * 32;
    unsigned short* lB0 = lB + (w * 16) * 32;
    unsigned short* lB1 = lB + (64 + w * 16) * 32;

    for (int kt = 0; kt < 1024; kt += 32) {
        __syncthreads();
        gll16(Ag0 + kt, lA0);
        gll16(Ag1 + kt, lA1);
        gll16(Bg0 + kt, lB0);
        gll16(Bg1 + kt, lB1);
        __syncthreads();
        bf16x8 af[4], bfr[4];
#pragma unroll
        for (int i = 0; i < 4; i++) {
            af[i]  = *(const bf16x8*)(lA + (wm + i * 16 + l15) * 32 + quad * 8);
            bfr[i] = *(const bf16x8*)(lB + (wn + i * 16 + l15) * 32 + quad * 8);
        }
#pragma unroll
        for (int i = 0; i < 4; i++)
#pragma unroll
            for (int j = 0; j < 4; j++)
                acc[i][j] = __builtin_amdgcn_mfma_f32_16x16x32_bf16(bfr[j], af[i], acc[i][j], 0, 0, 0);
    }

    // swapped D: lane holds 4 consecutive n at fixed s -> float4 stores
#pragma unroll
    for (int j = 0; j < 4; j++) {
        const int nbase = n0 + wn + j * 16 + quad * 4;
        const float4 bv4 = *(const float4*)(bo + nbase);
#pragma unroll
        for (int i = 0; i < 4; i++) {
            const int s = m0 + wm + i * 16 + l15;
            float4 v;
            v.x = acc[i][j][0] + bv4.x;
            v.y = acc[i][j][1] + bv4.y;
            v.z = acc[i][j][2] + bv4.z;
            v.w = acc[i][j][3] + bv4.w;
            *(float4*)(out + (size_t)s * 1024 + nbase) = v;
        }
    }
}

// ---------------- launch ----------------

extern "C" void kernel_launch(void* const* d_in, const int* in_sizes, int n_in,
                              void* d_out, int out_size, void* d_ws, size_t ws_size,
                              hipStream_t stream) {
    const float* x  = (const float*)d_in[0];
    const float* WQ = (const float*)d_in[1];
    const float* WK = (const float*)d_in[2];
    const float* WV = (const float*)d_in[3];
    const float* WO = (const float*)d_in[4];
    const float* bQ = (const float*)d_in[5];
    const float* bK = (const float*)d_in[6];
    const float* bV = (const float*)d_in[7];
    const float* bO = (const float*)d_in[8];
    float* out = (float*)d_out;

    char* ws = (char*)d_ws;
    unsigned short* xb   = (unsigned short*)ws;                   // 16 MB (reused as zbuf)
    unsigned short* wqkv = (unsigned short*)(ws + (16u << 20));   // 6 MB
    unsigned short* woT  = (unsigned short*)(ws + (22u << 20));   // 2 MB
    unsigned short* qws  = (unsigned short*)(ws + (24u << 20));   // 16 MB
    unsigned short* kws  = (unsigned short*)(ws + (40u << 20));   // 16 MB
    unsigned short* vtw  = (unsigned short*)(ws + (56u << 20));   // 16 MB, [bh][64][2048]
    unsigned short* zbuf = xb;                                    // x dead after gemm_qkv

    pack_x<<<8192, 256, 0, stream>>>(x, xb);
    pack_wqkv<<<(3072 * 1024) / 256, 256, 0, stream>>>(WQ, WK, WV, wqkv);
    pack_wo<<<(1024 * 1024) / 256, 256, 0, stream>>>(WO, woT);
    gemm_qkv<<<dim3(24, 64), 256, 0, stream>>>(xb, wqkv, bQ, bK, bV, qws, kws, vtw);
    attn3<<<2048, 256, 0, stream>>>(qws, kws, vtw, zbuf);
    gemm_out<<<dim3(8, 64), 256, 0, stream>>>(zbuf, woT, bO, out);
}